// Round 8
// baseline (379.602 us; speedup 1.0000x reference)
//
#include <hip/hip_runtime.h>

#define NN 100000
#define NE 1600000
#define DD 64
#define PAD 32                             // counters 1 per 128B line
#define NOCT 12500                         // NN / 8 nodes-per-wave (gemm)
#define SCAN_BS 256
#define NBLK ((NN + SCAN_BS - 1) / SCAN_BS)   // 391

// ---------------- zero ----------------
__global__ void zero_kernel(int* __restrict__ p, int n) {
  int i = blockIdx.x * blockDim.x + threadIdx.x;
  int stride = gridDim.x * blockDim.x;
  for (; i < n; i += stride) p[i] = 0;
}

// ---------------- degree histogram + rank record (at atomic-transaction floor)
__global__ void hist_kernel(const int* __restrict__ dst, int* __restrict__ degp,
                            int* __restrict__ rank) {
  const int NQ = NE / 4;                   // 400000
  int t = blockIdx.x * 256 + threadIdx.x;
  int nt = gridDim.x * 256;
  bool p0 = t < NQ, p1 = t + nt < NQ, p2 = t + 2 * nt < NQ, p3 = t + 3 * nt < NQ;
  int4 d0, d1, d2, d3;
  if (p0) d0 = reinterpret_cast<const int4*>(dst)[t];
  if (p1) d1 = reinterpret_cast<const int4*>(dst)[t + nt];
  if (p2) d2 = reinterpret_cast<const int4*>(dst)[t + 2 * nt];
  if (p3) d3 = reinterpret_cast<const int4*>(dst)[t + 3 * nt];
  int4 r0, r1, r2, r3;
  if (p0) {
    r0.x = atomicAdd(&degp[d0.x * PAD], 1);
    r0.y = atomicAdd(&degp[d0.y * PAD], 1);
    r0.z = atomicAdd(&degp[d0.z * PAD], 1);
    r0.w = atomicAdd(&degp[d0.w * PAD], 1);
  }
  if (p1) {
    r1.x = atomicAdd(&degp[d1.x * PAD], 1);
    r1.y = atomicAdd(&degp[d1.y * PAD], 1);
    r1.z = atomicAdd(&degp[d1.z * PAD], 1);
    r1.w = atomicAdd(&degp[d1.w * PAD], 1);
  }
  if (p2) {
    r2.x = atomicAdd(&degp[d2.x * PAD], 1);
    r2.y = atomicAdd(&degp[d2.y * PAD], 1);
    r2.z = atomicAdd(&degp[d2.z * PAD], 1);
    r2.w = atomicAdd(&degp[d2.w * PAD], 1);
  }
  if (p3) {
    r3.x = atomicAdd(&degp[d3.x * PAD], 1);
    r3.y = atomicAdd(&degp[d3.y * PAD], 1);
    r3.z = atomicAdd(&degp[d3.z * PAD], 1);
    r3.w = atomicAdd(&degp[d3.w * PAD], 1);
  }
  if (p0) reinterpret_cast<int4*>(rank)[t] = r0;
  if (p1) reinterpret_cast<int4*>(rank)[t + nt] = r1;
  if (p2) reinterpret_cast<int4*>(rank)[t + 2 * nt] = r2;
  if (p3) reinterpret_cast<int4*>(rank)[t + 3 * nt] = r3;
}

// ---------------- scan stage 1 (reads padded degp, emits compact degc) ------
__global__ void scan1_kernel(const int* __restrict__ degp, int* __restrict__ degc,
                             int* __restrict__ off, int* __restrict__ bsum) {
  __shared__ int wsum[4];
  int i = blockIdx.x * SCAN_BS + threadIdx.x;
  int lane = threadIdx.x & 63, g = threadIdx.x >> 6;
  int v = (i < NN) ? degp[i * PAD] : 0;
  if (i < NN) degc[i] = v;
  int incl = v;
  #pragma unroll
  for (int o = 1; o < 64; o <<= 1) {
    int t = __shfl_up(incl, o, 64);
    if (lane >= o) incl += t;
  }
  if (lane == 63) wsum[g] = incl;
  __syncthreads();
  int prefix = 0;
  for (int w = 0; w < g; ++w) prefix += wsum[w];
  if (i < NN) off[i] = prefix + incl - v;
  if (threadIdx.x == SCAN_BS - 1) bsum[blockIdx.x] = prefix + incl;
}

// ---------------- scan stage 2 ----------------
__global__ void scan2_kernel(int* __restrict__ bsum) {
  __shared__ int tmp[512];
  int i = threadIdx.x;
  int v = (i < NBLK) ? bsum[i] : 0;
  tmp[i] = v;
  __syncthreads();
  for (int o = 1; o < 512; o <<= 1) {
    int t = (i >= o) ? tmp[i - o] : 0;
    __syncthreads();
    tmp[i] += t;
    __syncthreads();
  }
  if (i < NBLK) bsum[i] = tmp[i] - v;
}

// ---------------- scan stage 3 ----------------
__global__ void scan3_kernel(int* __restrict__ off, const int* __restrict__ bsum) {
  int i = blockIdx.x * SCAN_BS + threadIdx.x;
  if (i < NN) off[i] += bsum[blockIdx.x];
}

// ---------------- CSR fill: NO atomics ----------------
__global__ void fill_kernel(const int* __restrict__ src, const int* __restrict__ dst,
                            const int* __restrict__ off, const int* __restrict__ rank,
                            int* __restrict__ adj) {
  int e4 = blockIdx.x * 256 + threadIdx.x;
  if (e4 >= NE / 4) return;
  int4 d = reinterpret_cast<const int4*>(dst)[e4];
  int4 s = reinterpret_cast<const int4*>(src)[e4];
  int4 r = reinterpret_cast<const int4*>(rank)[e4];
  adj[off[d.x] + r.x] = s.x;
  adj[off[d.y] + r.y] = s.y;
  adj[off[d.z] + r.z] = s.z;
  adj[off[d.w] + r.w] = s.w;
}

// ---------------- gather-mean, 4 nodes/wave, float4 rows --------------------
// Lane = (group g = lane/16 -> node, sublane s = lane%16 -> 16B of the row).
// One load instruction covers 4 neighbor rows (1KB); unroll 4 -> 16 rows
// (4KB) in flight per wave. No cross-group reduction; full-wave 1KB store.
__launch_bounds__(256)
__global__ void gather_kernel(const float* __restrict__ x,
                              const int* __restrict__ off,
                              const int* __restrict__ deg,
                              const int* __restrict__ adj,
                              float* __restrict__ prop) {
  const float4* X = reinterpret_cast<const float4*>(x);
  int wid = (blockIdx.x * 256 + threadIdx.x) >> 6;
  int nwaves = (gridDim.x * 256) >> 6;
  int lane = threadIdx.x & 63;
  int g = lane >> 4;                 // node within quad
  int s = lane & 15;                 // float4 slot within row
  const int NQUAD = NN / 4;          // 25000
  for (int q = wid; q < NQUAD; q += nwaves) {
    int n = q * 4 + g;
    int start = off[n];
    int d = deg[n];
    float4 a0 = {0,0,0,0}, a1 = {0,0,0,0}, a2 = {0,0,0,0}, a3 = {0,0,0,0};
    int t = 0;
    for (; t + 4 <= d; t += 4) {
      int i0 = adj[start + t + 0];
      int i1 = adj[start + t + 1];
      int i2 = adj[start + t + 2];
      int i3 = adj[start + t + 3];
      float4 v0 = X[i0 * 16 + s];
      float4 v1 = X[i1 * 16 + s];
      float4 v2 = X[i2 * 16 + s];
      float4 v3 = X[i3 * 16 + s];
      a0.x += v0.x; a0.y += v0.y; a0.z += v0.z; a0.w += v0.w;
      a1.x += v1.x; a1.y += v1.y; a1.z += v1.z; a1.w += v1.w;
      a2.x += v2.x; a2.y += v2.y; a2.z += v2.z; a2.w += v2.w;
      a3.x += v3.x; a3.y += v3.y; a3.z += v3.z; a3.w += v3.w;
    }
    if (t < d) {                     // tail <=3 rows, clamp + mask
      int dm = d - 1;
      int u1 = (t + 1 < d) ? t + 1 : dm;
      int u2 = (t + 2 < d) ? t + 2 : dm;
      int i0 = adj[start + t];
      int i1 = adj[start + u1];
      int i2 = adj[start + u2];
      float4 v0 = X[i0 * 16 + s];
      float4 v1 = X[i1 * 16 + s];
      float4 v2 = X[i2 * 16 + s];
      a0.x += v0.x; a0.y += v0.y; a0.z += v0.z; a0.w += v0.w;
      if (t + 1 < d) { a1.x += v1.x; a1.y += v1.y; a1.z += v1.z; a1.w += v1.w; }
      if (t + 2 < d) { a2.x += v2.x; a2.y += v2.y; a2.z += v2.z; a2.w += v2.w; }
    }
    float rc = 1.0f / fmaxf((float)d, 1.0f);
    float4 r;
    r.x = ((a0.x + a1.x) + (a2.x + a3.x)) * rc;
    r.y = ((a0.y + a1.y) + (a2.y + a3.y)) * rc;
    r.z = ((a0.z + a1.z) + (a2.z + a3.z)) * rc;
    r.w = ((a0.w + a1.w) + (a2.w + a3.w)) * rc;
    reinterpret_cast<float4*>(prop)[n * 16 + s] = r;   // 1KB/wave contiguous
  }
}

// ---------------- dense SAGE GEMM (+optional fused post-MLP) ----------------
// out = relu(norm(x@wl.T + prop@wr.T + b));  if POST: out = out@wc.T + bc
// 8 waves x 8 nodes; wave-local staging -> no in-loop syncs. In-place safe.
template <bool POST>
__launch_bounds__(512, 2)
__global__ void sage_gemm_kernel(const float* __restrict__ xin,
                                 const float* __restrict__ prop,
                                 const float* __restrict__ wl,
                                 const float* __restrict__ bl,
                                 const float* __restrict__ wr,
                                 const float* __restrict__ br,
                                 const float* __restrict__ wc,
                                 const float* __restrict__ bc,
                                 float* __restrict__ out) {
  __shared__ float wlA[DD * DD] __attribute__((aligned(16)));  // [k][j]
  __shared__ float wrA[DD * DD] __attribute__((aligned(16)));  // [k][j]
  __shared__ float wcA[DD * DD] __attribute__((aligned(16)));  // [k][j] (POST)
  __shared__ float sp[8][8][DD] __attribute__((aligned(16)));
  __shared__ float pp[8][8][DD] __attribute__((aligned(16)));
  int tid = threadIdx.x;
  int j = tid & 63;
  int w = tid >> 6;

  for (int i = tid; i < DD * DD; i += 512) {
    int jj = i >> 6, kk = i & 63;
    wlA[kk * DD + jj] = wl[i];
    wrA[kk * DD + jj] = wr[i];
    if (POST) wcA[kk * DD + jj] = wc[i];
  }
  float bias = bl[j] + br[j];
  float bcv = POST ? bc[j] : 0.0f;
  __syncthreads();

  const int ngrp = (NOCT + 7) / 8;   // 1563
  for (int grp = blockIdx.x; grp < ngrp; grp += gridDim.x) {
    int o = grp * 8 + w;
    if (o >= NOCT) continue;
    int n0 = o * 8;

    #pragma unroll
    for (int i = 0; i < 8; ++i) {
      sp[w][i][j] = xin[(size_t)(n0 + i) * DD + j];
      pp[w][i][j] = prop[(size_t)(n0 + i) * DD + j];
    }

    float acc[8];
    #pragma unroll
    for (int i = 0; i < 8; ++i) acc[i] = bias;

    #pragma unroll
    for (int q = 0; q < 16; ++q) {
      int kb = q * 4;
      float wl0 = wlA[(kb + 0) * DD + j];
      float wl1 = wlA[(kb + 1) * DD + j];
      float wl2 = wlA[(kb + 2) * DD + j];
      float wl3 = wlA[(kb + 3) * DD + j];
      float wr0 = wrA[(kb + 0) * DD + j];
      float wr1 = wrA[(kb + 1) * DD + j];
      float wr2 = wrA[(kb + 2) * DD + j];
      float wr3 = wrA[(kb + 3) * DD + j];
      #pragma unroll
      for (int i = 0; i < 8; ++i) {
        float4 sv = *(const float4*)&sp[w][i][kb];   // broadcast
        float4 pv = *(const float4*)&pp[w][i][kb];   // broadcast
        float a = acc[i];
        a = fmaf(sv.x, wl0, a);
        a = fmaf(sv.y, wl1, a);
        a = fmaf(sv.z, wl2, a);
        a = fmaf(sv.w, wl3, a);
        a = fmaf(pv.x, wr0, a);
        a = fmaf(pv.y, wr1, a);
        a = fmaf(pv.z, wr2, a);
        a = fmaf(pv.w, wr3, a);
        acc[i] = a;
      }
    }

    // L2 normalize + relu
    #pragma unroll
    for (int i = 0; i < 8; ++i) {
      float a = acc[i];
      float ss = a * a;
      #pragma unroll
      for (int o2 = 32; o2 > 0; o2 >>= 1) ss += __shfl_xor(ss, o2, 64);
      float ov = a / fmaxf(sqrtf(ss), 1e-12f);
      ov = fmaxf(ov, 0.0f);
      if (POST) sp[w][i][j] = ov;                    // stage for post GEMM
      else out[(size_t)(n0 + i) * DD + j] = ov;
    }

    if (POST) {
      float acc2[8];
      #pragma unroll
      for (int i = 0; i < 8; ++i) acc2[i] = bcv;
      #pragma unroll
      for (int q = 0; q < 16; ++q) {
        int kb = q * 4;
        float w0 = wcA[(kb + 0) * DD + j];
        float w1v = wcA[(kb + 1) * DD + j];
        float w2v = wcA[(kb + 2) * DD + j];
        float w3v = wcA[(kb + 3) * DD + j];
        #pragma unroll
        for (int i = 0; i < 8; ++i) {
          float4 hv = *(const float4*)&sp[w][i][kb];
          float a = acc2[i];
          a = fmaf(hv.x, w0, a);
          a = fmaf(hv.y, w1v, a);
          a = fmaf(hv.z, w2v, a);
          a = fmaf(hv.w, w3v, a);
          acc2[i] = a;
        }
      }
      #pragma unroll
      for (int i = 0; i < 8; ++i) out[(size_t)(n0 + i) * DD + j] = acc2[i];
    }
  }
}

// ---------------- combine post weights: wc = w2@w1, bc = w2@b1 + b2 ---------
__global__ void combine_kernel(const float* __restrict__ w1, const float* __restrict__ b1,
                               const float* __restrict__ w2, const float* __restrict__ b2,
                               float* __restrict__ wc, float* __restrict__ bc) {
  int t = threadIdx.x;
  for (int idx = t; idx < DD * DD; idx += 512) {
    int jp = idx >> 6, k = idx & 63;
    float s = 0.f;
    #pragma unroll
    for (int m = 0; m < DD; ++m) s = fmaf(w2[jp * DD + m], w1[m * DD + k], s);
    wc[idx] = s;
  }
  if (t < DD) {
    float s = b2[t];
    #pragma unroll
    for (int m = 0; m < DD; ++m) s = fmaf(w2[t * DD + m], b1[m], s);
    bc[t] = s;
  }
}

extern "C" void kernel_launch(void* const* d_in, const int* in_sizes, int n_in,
                              void* d_out, int out_size, void* d_ws, size_t ws_size,
                              hipStream_t stream) {
  const float* x   = (const float*)d_in[0];
  const int*   ei  = (const int*)d_in[1];
  const float* w1l = (const float*)d_in[2];
  const float* b1l = (const float*)d_in[3];
  const float* w1r = (const float*)d_in[4];
  const float* b1r = (const float*)d_in[5];
  const float* w2l = (const float*)d_in[6];
  const float* b2l = (const float*)d_in[7];
  const float* w2r = (const float*)d_in[8];
  const float* b2r = (const float*)d_in[9];
  const float* wp1 = (const float*)d_in[10];
  const float* bp1 = (const float*)d_in[11];
  const float* wp2 = (const float*)d_in[12];
  const float* bp2 = (const float*)d_in[13];
  float* out = (float*)d_out;

  const int* src = ei;
  const int* dst = ei + NE;

  // ws (4B units): degc[102400] | off[102400] | bsum[1024] | wc[4096] | bc[1024]
  //               | adj[NE] | prop[NN*DD]
  // Aliased into prop (dead before gather writes prop):
  //   rank = prop[0 .. NE) ; degp = prop[NE .. NE+NN*PAD)
  int* degc  = (int*)d_ws;
  int* off   = degc + 102400;
  int* bsum  = off + 102400;
  float* wc  = (float*)(bsum + 1024);
  float* bc  = wc + 4096;
  int* adj   = (int*)(bc + 1024);
  float* prop = (float*)(adj + NE);
  int* rank  = (int*)prop;                 // [NE]
  int* degp  = rank + NE;                  // [NN*PAD]

  const int e4grid = (NE / 4 + 255) / 256;   // 1563

  // ---- build CSR once ----
  zero_kernel<<<2048, 256, 0, stream>>>(degp, NN * PAD);
  hist_kernel<<<NBLK, 256, 0, stream>>>(dst, degp, rank);
  scan1_kernel<<<NBLK, SCAN_BS, 0, stream>>>(degp, degc, off, bsum);
  scan2_kernel<<<1, 512, 0, stream>>>(bsum);
  scan3_kernel<<<NBLK, SCAN_BS, 0, stream>>>(off, bsum);
  fill_kernel<<<e4grid, 256, 0, stream>>>(src, dst, off, rank, adj);
  combine_kernel<<<1, 512, 0, stream>>>(wp1, bp1, wp2, bp2, wc, bc);

  // ---- layer 1: gather(x)->prop; gemm(x,prop)->out ----
  gather_kernel<<<2048, 256, 0, stream>>>(x, off, degc, adj, prop);
  sage_gemm_kernel<false><<<512, 512, 0, stream>>>(x, prop, w1l, b1l, w1r, b1r,
                                                   nullptr, nullptr, out);

  // ---- layer 2 + fused post: gather(out)->prop; gemm+post -> out ----
  gather_kernel<<<2048, 256, 0, stream>>>(out, off, degc, adj, prop);
  sage_gemm_kernel<true><<<512, 512, 0, stream>>>(out, prop, w2l, b2l, w2r, b2r,
                                                  wc, bc, out);
}

// Round 9
// 371.916 us; speedup vs baseline: 1.0207x; 1.0207x over previous
//
#include <hip/hip_runtime.h>

#define NN 100000
#define NE 1600000
#define DD 64
#define NOCT 12500                         // NN / 8 nodes-per-wave (gemm)
#define SCAN_BS 256
#define NBLK ((NN + SCAN_BS - 1) / SCAN_BS)   // 391

// ---------------- zero ----------------
__global__ void zero_kernel(int* __restrict__ p, int n) {
  int i = blockIdx.x * blockDim.x + threadIdx.x;
  int stride = gridDim.x * blockDim.x;
  for (; i < n; i += stride) p[i] = 0;
}

// ---------------- degree histogram + rank record -----------------------------
// At the chip returning-atomic floor (~25G/s); layout/occupancy insensitive.
__global__ void hist_kernel(const int* __restrict__ dst, int* __restrict__ deg,
                            int* __restrict__ rank) {
  const int NQ = NE / 4;                   // 400000
  int t = blockIdx.x * 256 + threadIdx.x;
  int nt = gridDim.x * 256;
  bool p0 = t < NQ, p1 = t + nt < NQ, p2 = t + 2 * nt < NQ, p3 = t + 3 * nt < NQ;
  int4 d0, d1, d2, d3;
  if (p0) d0 = reinterpret_cast<const int4*>(dst)[t];
  if (p1) d1 = reinterpret_cast<const int4*>(dst)[t + nt];
  if (p2) d2 = reinterpret_cast<const int4*>(dst)[t + 2 * nt];
  if (p3) d3 = reinterpret_cast<const int4*>(dst)[t + 3 * nt];
  int4 r0, r1, r2, r3;
  if (p0) {
    r0.x = atomicAdd(&deg[d0.x], 1);
    r0.y = atomicAdd(&deg[d0.y], 1);
    r0.z = atomicAdd(&deg[d0.z], 1);
    r0.w = atomicAdd(&deg[d0.w], 1);
  }
  if (p1) {
    r1.x = atomicAdd(&deg[d1.x], 1);
    r1.y = atomicAdd(&deg[d1.y], 1);
    r1.z = atomicAdd(&deg[d1.z], 1);
    r1.w = atomicAdd(&deg[d1.w], 1);
  }
  if (p2) {
    r2.x = atomicAdd(&deg[d2.x], 1);
    r2.y = atomicAdd(&deg[d2.y], 1);
    r2.z = atomicAdd(&deg[d2.z], 1);
    r2.w = atomicAdd(&deg[d2.w], 1);
  }
  if (p3) {
    r3.x = atomicAdd(&deg[d3.x], 1);
    r3.y = atomicAdd(&deg[d3.y], 1);
    r3.z = atomicAdd(&deg[d3.z], 1);
    r3.w = atomicAdd(&deg[d3.w], 1);
  }
  if (p0) reinterpret_cast<int4*>(rank)[t] = r0;
  if (p1) reinterpret_cast<int4*>(rank)[t + nt] = r1;
  if (p2) reinterpret_cast<int4*>(rank)[t + 2 * nt] = r2;
  if (p3) reinterpret_cast<int4*>(rank)[t + 3 * nt] = r3;
}

// ---------------- scan stage 1 ----------------
__global__ void scan1_kernel(const int* __restrict__ deg, int* __restrict__ off,
                             int* __restrict__ bsum) {
  __shared__ int wsum[4];
  int i = blockIdx.x * SCAN_BS + threadIdx.x;
  int lane = threadIdx.x & 63, g = threadIdx.x >> 6;
  int v = (i < NN) ? deg[i] : 0;
  int incl = v;
  #pragma unroll
  for (int o = 1; o < 64; o <<= 1) {
    int t = __shfl_up(incl, o, 64);
    if (lane >= o) incl += t;
  }
  if (lane == 63) wsum[g] = incl;
  __syncthreads();
  int prefix = 0;
  for (int w = 0; w < g; ++w) prefix += wsum[w];
  if (i < NN) off[i] = prefix + incl - v;
  if (threadIdx.x == SCAN_BS - 1) bsum[blockIdx.x] = prefix + incl;
}

// ---------------- scan stage 2 ----------------
__global__ void scan2_kernel(int* __restrict__ bsum) {
  __shared__ int tmp[512];
  int i = threadIdx.x;
  int v = (i < NBLK) ? bsum[i] : 0;
  tmp[i] = v;
  __syncthreads();
  for (int o = 1; o < 512; o <<= 1) {
    int t = (i >= o) ? tmp[i - o] : 0;
    __syncthreads();
    tmp[i] += t;
    __syncthreads();
  }
  if (i < NBLK) bsum[i] = tmp[i] - v;
}

// ---------------- scan stage 3 ----------------
__global__ void scan3_kernel(int* __restrict__ off, const int* __restrict__ bsum) {
  int i = blockIdx.x * SCAN_BS + threadIdx.x;
  if (i < NN) off[i] += bsum[blockIdx.x];
}

// ---------------- CSR fill: NO atomics ----------------
__global__ void fill_kernel(const int* __restrict__ src, const int* __restrict__ dst,
                            const int* __restrict__ off, const int* __restrict__ rank,
                            int* __restrict__ adj) {
  int e4 = blockIdx.x * 256 + threadIdx.x;
  if (e4 >= NE / 4) return;
  int4 d = reinterpret_cast<const int4*>(dst)[e4];
  int4 s = reinterpret_cast<const int4*>(src)[e4];
  int4 r = reinterpret_cast<const int4*>(rank)[e4];
  adj[off[d.x] + r.x] = s.x;
  adj[off[d.y] + r.y] = s.y;
  adj[off[d.z] + r.z] = s.z;
  adj[off[d.w] + r.w] = s.w;
}

// ---------------- gather-mean, 4 nodes/wave, float4 rows --------------------
__launch_bounds__(256)
__global__ void gather_kernel(const float* __restrict__ x,
                              const int* __restrict__ off,
                              const int* __restrict__ deg,
                              const int* __restrict__ adj,
                              float* __restrict__ prop) {
  const float4* X = reinterpret_cast<const float4*>(x);
  int wid = (blockIdx.x * 256 + threadIdx.x) >> 6;
  int nwaves = (gridDim.x * 256) >> 6;
  int lane = threadIdx.x & 63;
  int g = lane >> 4;                 // node within quad
  int s = lane & 15;                 // float4 slot within row
  const int NQUAD = NN / 4;          // 25000
  for (int q = wid; q < NQUAD; q += nwaves) {
    int n = q * 4 + g;
    int start = off[n];
    int d = deg[n];
    float4 a0 = {0,0,0,0}, a1 = {0,0,0,0}, a2 = {0,0,0,0}, a3 = {0,0,0,0};
    int t = 0;
    for (; t + 4 <= d; t += 4) {
      int i0 = adj[start + t + 0];
      int i1 = adj[start + t + 1];
      int i2 = adj[start + t + 2];
      int i3 = adj[start + t + 3];
      float4 v0 = X[i0 * 16 + s];
      float4 v1 = X[i1 * 16 + s];
      float4 v2 = X[i2 * 16 + s];
      float4 v3 = X[i3 * 16 + s];
      a0.x += v0.x; a0.y += v0.y; a0.z += v0.z; a0.w += v0.w;
      a1.x += v1.x; a1.y += v1.y; a1.z += v1.z; a1.w += v1.w;
      a2.x += v2.x; a2.y += v2.y; a2.z += v2.z; a2.w += v2.w;
      a3.x += v3.x; a3.y += v3.y; a3.z += v3.z; a3.w += v3.w;
    }
    if (t < d) {                     // tail <=3 rows, clamp + mask
      int dm = d - 1;
      int u1 = (t + 1 < d) ? t + 1 : dm;
      int u2 = (t + 2 < d) ? t + 2 : dm;
      int i0 = adj[start + t];
      int i1 = adj[start + u1];
      int i2 = adj[start + u2];
      float4 v0 = X[i0 * 16 + s];
      float4 v1 = X[i1 * 16 + s];
      float4 v2 = X[i2 * 16 + s];
      a0.x += v0.x; a0.y += v0.y; a0.z += v0.z; a0.w += v0.w;
      if (t + 1 < d) { a1.x += v1.x; a1.y += v1.y; a1.z += v1.z; a1.w += v1.w; }
      if (t + 2 < d) { a2.x += v2.x; a2.y += v2.y; a2.z += v2.z; a2.w += v2.w; }
    }
    float rc = 1.0f / fmaxf((float)d, 1.0f);
    float4 r;
    r.x = ((a0.x + a1.x) + (a2.x + a3.x)) * rc;
    r.y = ((a0.y + a1.y) + (a2.y + a3.y)) * rc;
    r.z = ((a0.z + a1.z) + (a2.z + a3.z)) * rc;
    r.w = ((a0.w + a1.w) + (a2.w + a3.w)) * rc;
    reinterpret_cast<float4*>(prop)[n * 16 + s] = r;   // 1KB/wave contiguous
  }
}

// ---------------- dense SAGE GEMM: out = relu(norm(x@wl.T + prop@wr.T + b)) --
// 8 waves x 8 nodes; wave-local staging -> no in-loop syncs. LDS = 64KB ->
// 2 blocks/CU at (512,4). In-place safe (row-local).
__launch_bounds__(512, 4)
__global__ void sage_gemm_kernel(const float* __restrict__ xin,
                                 const float* __restrict__ prop,
                                 const float* __restrict__ wl,
                                 const float* __restrict__ bl,
                                 const float* __restrict__ wr,
                                 const float* __restrict__ br,
                                 float* __restrict__ out) {
  __shared__ float wlA[DD * DD] __attribute__((aligned(16)));  // [k][j]
  __shared__ float wrA[DD * DD] __attribute__((aligned(16)));  // [k][j]
  __shared__ float sp[8][8][DD] __attribute__((aligned(16)));
  __shared__ float pp[8][8][DD] __attribute__((aligned(16)));
  int tid = threadIdx.x;
  int j = tid & 63;
  int w = tid >> 6;

  for (int i = tid; i < DD * DD; i += 512) {
    int jj = i >> 6, kk = i & 63;
    wlA[kk * DD + jj] = wl[i];
    wrA[kk * DD + jj] = wr[i];
  }
  float bias = bl[j] + br[j];
  __syncthreads();

  const int ngrp = (NOCT + 7) / 8;   // 1563
  for (int grp = blockIdx.x; grp < ngrp; grp += gridDim.x) {
    int o = grp * 8 + w;
    if (o >= NOCT) continue;
    int n0 = o * 8;

    #pragma unroll
    for (int i = 0; i < 8; ++i) {
      sp[w][i][j] = xin[(size_t)(n0 + i) * DD + j];
      pp[w][i][j] = prop[(size_t)(n0 + i) * DD + j];
    }

    float acc[8];
    #pragma unroll
    for (int i = 0; i < 8; ++i) acc[i] = bias;

    #pragma unroll
    for (int q = 0; q < 16; ++q) {
      int kb = q * 4;
      float wl0 = wlA[(kb + 0) * DD + j];
      float wl1 = wlA[(kb + 1) * DD + j];
      float wl2 = wlA[(kb + 2) * DD + j];
      float wl3 = wlA[(kb + 3) * DD + j];
      float wr0 = wrA[(kb + 0) * DD + j];
      float wr1 = wrA[(kb + 1) * DD + j];
      float wr2 = wrA[(kb + 2) * DD + j];
      float wr3 = wrA[(kb + 3) * DD + j];
      #pragma unroll
      for (int i = 0; i < 8; ++i) {
        float4 sv = *(const float4*)&sp[w][i][kb];   // broadcast
        float4 pv = *(const float4*)&pp[w][i][kb];   // broadcast
        float a = acc[i];
        a = fmaf(sv.x, wl0, a);
        a = fmaf(sv.y, wl1, a);
        a = fmaf(sv.z, wl2, a);
        a = fmaf(sv.w, wl3, a);
        a = fmaf(pv.x, wr0, a);
        a = fmaf(pv.y, wr1, a);
        a = fmaf(pv.z, wr2, a);
        a = fmaf(pv.w, wr3, a);
        acc[i] = a;
      }
    }

    #pragma unroll
    for (int i = 0; i < 8; ++i) {
      float a = acc[i];
      float ss = a * a;
      #pragma unroll
      for (int o2 = 32; o2 > 0; o2 >>= 1) ss += __shfl_xor(ss, o2, 64);
      float ov = a / fmaxf(sqrtf(ss), 1e-12f);
      ov = fmaxf(ov, 0.0f);
      out[(size_t)(n0 + i) * DD + j] = ov;
    }
  }
}

// ---------------- combine post weights: wc = w2@w1, bc = w2@b1 + b2 ---------
__global__ void combine_kernel(const float* __restrict__ w1, const float* __restrict__ b1,
                               const float* __restrict__ w2, const float* __restrict__ b2,
                               float* __restrict__ wc, float* __restrict__ bc) {
  int t = threadIdx.x;
  for (int idx = t; idx < DD * DD; idx += 512) {
    int jp = idx >> 6, k = idx & 63;
    float s = 0.f;
    #pragma unroll
    for (int m = 0; m < DD; ++m) s = fmaf(w2[jp * DD + m], w1[m * DD + k], s);
    wc[idx] = s;
  }
  if (t < DD) {
    float s = b2[t];
    #pragma unroll
    for (int m = 0; m < DD; ++m) s = fmaf(w2[t * DD + m], b1[m], s);
    bc[t] = s;
  }
}

// ---------------- post-MLP as a single folded GEMM (in-place safe) ----------
__launch_bounds__(512, 4)
__global__ void post_kernel(const float* __restrict__ h,
                            const float* __restrict__ wc,
                            const float* __restrict__ bc,
                            float* __restrict__ out) {
  __shared__ float wA[DD * DD] __attribute__((aligned(16)));   // [k][j]
  __shared__ float hp[8][8][DD] __attribute__((aligned(16)));
  int tid = threadIdx.x;
  int j = tid & 63;
  int w = tid >> 6;

  for (int i = tid; i < DD * DD; i += 512) {
    int jj = i >> 6, kk = i & 63;
    wA[kk * DD + jj] = wc[i];
  }
  float bb = bc[j];
  __syncthreads();

  const int ngrp = (NOCT + 7) / 8;
  for (int grp = blockIdx.x; grp < ngrp; grp += gridDim.x) {
    int o = grp * 8 + w;
    if (o >= NOCT) continue;
    int n0 = o * 8;
    #pragma unroll
    for (int i = 0; i < 8; ++i) hp[w][i][j] = h[(size_t)(n0 + i) * DD + j];

    float acc[8];
    #pragma unroll
    for (int i = 0; i < 8; ++i) acc[i] = bb;
    #pragma unroll
    for (int q = 0; q < 16; ++q) {
      int kb = q * 4;
      float w0 = wA[(kb + 0) * DD + j];
      float w1v = wA[(kb + 1) * DD + j];
      float w2v = wA[(kb + 2) * DD + j];
      float w3v = wA[(kb + 3) * DD + j];
      #pragma unroll
      for (int i = 0; i < 8; ++i) {
        float4 hv = *(const float4*)&hp[w][i][kb];
        float a = acc[i];
        a = fmaf(hv.x, w0, a);
        a = fmaf(hv.y, w1v, a);
        a = fmaf(hv.z, w2v, a);
        a = fmaf(hv.w, w3v, a);
        acc[i] = a;
      }
    }
    #pragma unroll
    for (int i = 0; i < 8; ++i) out[(size_t)(n0 + i) * DD + j] = acc[i];
  }
}

extern "C" void kernel_launch(void* const* d_in, const int* in_sizes, int n_in,
                              void* d_out, int out_size, void* d_ws, size_t ws_size,
                              hipStream_t stream) {
  const float* x   = (const float*)d_in[0];
  const int*   ei  = (const int*)d_in[1];
  const float* w1l = (const float*)d_in[2];
  const float* b1l = (const float*)d_in[3];
  const float* w1r = (const float*)d_in[4];
  const float* b1r = (const float*)d_in[5];
  const float* w2l = (const float*)d_in[6];
  const float* b2l = (const float*)d_in[7];
  const float* w2r = (const float*)d_in[8];
  const float* b2r = (const float*)d_in[9];
  const float* wp1 = (const float*)d_in[10];
  const float* bp1 = (const float*)d_in[11];
  const float* wp2 = (const float*)d_in[12];
  const float* bp2 = (const float*)d_in[13];
  float* out = (float*)d_out;

  const int* src = ei;
  const int* dst = ei + NE;

  // ws (4B units): deg[102400] | off[102400] | bsum[1024] | wc[4096] | bc[1024]
  //               | adj[NE] | prop[NN*DD]
  // rank aliases prop (dead before gather writes prop).
  int* deg   = (int*)d_ws;
  int* off   = deg + 102400;
  int* bsum  = off + 102400;
  float* wc  = (float*)(bsum + 1024);
  float* bc  = wc + 4096;
  int* adj   = (int*)(bc + 1024);
  float* prop = (float*)(adj + NE);
  int* rank  = (int*)prop;                 // [NE]

  const int e4grid = (NE / 4 + 255) / 256;   // 1563

  // ---- build CSR once ----
  zero_kernel<<<256, 256, 0, stream>>>(deg, 102400);
  hist_kernel<<<NBLK, 256, 0, stream>>>(dst, deg, rank);
  scan1_kernel<<<NBLK, SCAN_BS, 0, stream>>>(deg, off, bsum);
  scan2_kernel<<<1, 512, 0, stream>>>(bsum);
  scan3_kernel<<<NBLK, SCAN_BS, 0, stream>>>(off, bsum);
  fill_kernel<<<e4grid, 256, 0, stream>>>(src, dst, off, rank, adj);
  combine_kernel<<<1, 512, 0, stream>>>(wp1, bp1, wp2, bp2, wc, bc);

  // ---- layer 1: gather(x)->prop; gemm(x,prop)->out ----
  gather_kernel<<<2048, 256, 0, stream>>>(x, off, deg, adj, prop);
  sage_gemm_kernel<<<512, 512, 0, stream>>>(x, prop, w1l, b1l, w1r, b1r, out);

  // ---- layer 2: gather(out)->prop; gemm(out,prop)->out (in-place safe) ----
  gather_kernel<<<2048, 256, 0, stream>>>(out, off, deg, adj, prop);
  sage_gemm_kernel<<<512, 512, 0, stream>>>(out, prop, w2l, b2l, w2r, b2r, out);

  // ---- post-MLP (single folded GEMM, in-place) ----
  post_kernel<<<512, 512, 0, stream>>>(out, wc, bc, out);
}

// Round 10
// 357.909 us; speedup vs baseline: 1.0606x; 1.0391x over previous
//
#include <hip/hip_runtime.h>

#define NN 100000
#define NE 1600000
#define DD 64
#define NOCT 12500                         // NN / 8 nodes-per-wave (gemm)
#define SCAN_BS 256
#define NBLK ((NN + SCAN_BS - 1) / SCAN_BS)   // 391
#define NH 391                             // hist-role blocks in mega1
#define NG1 1024                           // self-GEMM-role blocks in mega1

// ---------------- zero ----------------
__global__ void zero_kernel(int* __restrict__ p, int n) {
  int i = blockIdx.x * blockDim.x + threadIdx.x;
  int stride = gridDim.x * blockDim.x;
  for (; i < n; i += stride) p[i] = 0;
}

// ---------------- mega1: hist+rank  ||  layer1 self-GEMM  ||  combine -------
// Role by blockIdx (wave-uniform):
//   [0, NH):        degree histogram + rank (returning-atomic floor ~65us,
//                   occupancy-insensitive -> other roles ride for free)
//   [NH, NH+NG1):   tmp1 = x @ w1l.T + (b1l + b1r)  -> written to d_out
//   NH+NG1:         wc = wp2@wp1, bc = wp2@bp1 + bp2
__launch_bounds__(256)
__global__ void mega1_kernel(const int* __restrict__ dst, int* __restrict__ deg,
                             int* __restrict__ rank,
                             const float* __restrict__ x,
                             const float* __restrict__ wl,
                             const float* __restrict__ bl,
                             const float* __restrict__ br,
                             float* __restrict__ tmp,
                             const float* __restrict__ wp1, const float* __restrict__ bp1,
                             const float* __restrict__ wp2, const float* __restrict__ bp2,
                             float* __restrict__ wc, float* __restrict__ bc) {
  __shared__ float wA[DD * DD] __attribute__((aligned(16)));   // 16KB (gemm role)
  __shared__ float sp[4][8][DD] __attribute__((aligned(16)));  // 8KB  (gemm role)
  int bid = blockIdx.x;

  if (bid < NH) {
    // ---- hist role ----
    const int NQ = NE / 4;                 // 400000
    int t = bid * 256 + threadIdx.x;
    const int nt = NH * 256;               // 100096
    bool p0 = t < NQ, p1 = t + nt < NQ, p2 = t + 2 * nt < NQ, p3 = t + 3 * nt < NQ;
    int4 d0, d1, d2, d3;
    if (p0) d0 = reinterpret_cast<const int4*>(dst)[t];
    if (p1) d1 = reinterpret_cast<const int4*>(dst)[t + nt];
    if (p2) d2 = reinterpret_cast<const int4*>(dst)[t + 2 * nt];
    if (p3) d3 = reinterpret_cast<const int4*>(dst)[t + 3 * nt];
    int4 r0, r1, r2, r3;
    if (p0) {
      r0.x = atomicAdd(&deg[d0.x], 1);
      r0.y = atomicAdd(&deg[d0.y], 1);
      r0.z = atomicAdd(&deg[d0.z], 1);
      r0.w = atomicAdd(&deg[d0.w], 1);
    }
    if (p1) {
      r1.x = atomicAdd(&deg[d1.x], 1);
      r1.y = atomicAdd(&deg[d1.y], 1);
      r1.z = atomicAdd(&deg[d1.z], 1);
      r1.w = atomicAdd(&deg[d1.w], 1);
    }
    if (p2) {
      r2.x = atomicAdd(&deg[d2.x], 1);
      r2.y = atomicAdd(&deg[d2.y], 1);
      r2.z = atomicAdd(&deg[d2.z], 1);
      r2.w = atomicAdd(&deg[d2.w], 1);
    }
    if (p3) {
      r3.x = atomicAdd(&deg[d3.x], 1);
      r3.y = atomicAdd(&deg[d3.y], 1);
      r3.z = atomicAdd(&deg[d3.z], 1);
      r3.w = atomicAdd(&deg[d3.w], 1);
    }
    if (p0) reinterpret_cast<int4*>(rank)[t] = r0;
    if (p1) reinterpret_cast<int4*>(rank)[t + nt] = r1;
    if (p2) reinterpret_cast<int4*>(rank)[t + 2 * nt] = r2;
    if (p3) reinterpret_cast<int4*>(rank)[t + 3 * nt] = r3;
  } else if (bid < NH + NG1) {
    // ---- layer1 self-GEMM role: tmp = x@wl.T + (bl+br) ----
    int vb = bid - NH;
    int tid = threadIdx.x;
    int j = tid & 63;
    int w = tid >> 6;                      // 0..3
    for (int i = tid; i < DD * DD; i += 256) {
      int jj = i >> 6, kk = i & 63;        // transposed: wA[k][j] = wl[j][k]
      wA[kk * DD + jj] = wl[i];
    }
    float bias = bl[j] + br[j];
    __syncthreads();
    const int ngrp = 3125;                 // 100000 / (4 waves * 8 nodes)
    for (int grp = vb; grp < ngrp; grp += NG1) {
      int n0 = (grp * 4 + w) * 8;
      #pragma unroll
      for (int i = 0; i < 8; ++i) sp[w][i][j] = x[(size_t)(n0 + i) * DD + j];
      float acc[8];
      #pragma unroll
      for (int i = 0; i < 8; ++i) acc[i] = bias;
      #pragma unroll
      for (int q = 0; q < 16; ++q) {
        int kb = q * 4;
        float w0 = wA[(kb + 0) * DD + j];
        float w1v = wA[(kb + 1) * DD + j];
        float w2v = wA[(kb + 2) * DD + j];
        float w3v = wA[(kb + 3) * DD + j];
        #pragma unroll
        for (int i = 0; i < 8; ++i) {
          float4 sv = *(const float4*)&sp[w][i][kb];   // broadcast
          float a = acc[i];
          a = fmaf(sv.x, w0, a);
          a = fmaf(sv.y, w1v, a);
          a = fmaf(sv.z, w2v, a);
          a = fmaf(sv.w, w3v, a);
          acc[i] = a;
        }
      }
      #pragma unroll
      for (int i = 0; i < 8; ++i) tmp[(size_t)(n0 + i) * DD + j] = acc[i];
    }
  } else {
    // ---- combine role: wc = wp2@wp1, bc = wp2@bp1 + bp2 ----
    int t = threadIdx.x;
    for (int idx = t; idx < DD * DD; idx += 256) {
      int jp = idx >> 6, k = idx & 63;
      float s = 0.f;
      #pragma unroll
      for (int m = 0; m < DD; ++m) s = fmaf(wp2[jp * DD + m], wp1[m * DD + k], s);
      wc[idx] = s;
    }
    if (t < DD) {
      float s = bp2[t];
      #pragma unroll
      for (int m = 0; m < DD; ++m) s = fmaf(wp2[t * DD + m], bp1[m], s);
      bc[t] = s;
    }
  }
}

// ---------------- scan stage 1 ----------------
__global__ void scan1_kernel(const int* __restrict__ deg, int* __restrict__ off,
                             int* __restrict__ bsum) {
  __shared__ int wsum[4];
  int i = blockIdx.x * SCAN_BS + threadIdx.x;
  int lane = threadIdx.x & 63, g = threadIdx.x >> 6;
  int v = (i < NN) ? deg[i] : 0;
  int incl = v;
  #pragma unroll
  for (int o = 1; o < 64; o <<= 1) {
    int t = __shfl_up(incl, o, 64);
    if (lane >= o) incl += t;
  }
  if (lane == 63) wsum[g] = incl;
  __syncthreads();
  int prefix = 0;
  for (int w = 0; w < g; ++w) prefix += wsum[w];
  if (i < NN) off[i] = prefix + incl - v;
  if (threadIdx.x == SCAN_BS - 1) bsum[blockIdx.x] = prefix + incl;
}

// ---------------- scan stage 2 ----------------
__global__ void scan2_kernel(int* __restrict__ bsum) {
  __shared__ int tmp[512];
  int i = threadIdx.x;
  int v = (i < NBLK) ? bsum[i] : 0;
  tmp[i] = v;
  __syncthreads();
  for (int o = 1; o < 512; o <<= 1) {
    int t = (i >= o) ? tmp[i - o] : 0;
    __syncthreads();
    tmp[i] += t;
    __syncthreads();
  }
  if (i < NBLK) bsum[i] = tmp[i] - v;
}

// ---------------- scan stage 3 ----------------
__global__ void scan3_kernel(int* __restrict__ off, const int* __restrict__ bsum) {
  int i = blockIdx.x * SCAN_BS + threadIdx.x;
  if (i < NN) off[i] += bsum[blockIdx.x];
}

// ---------------- CSR fill: NO atomics ----------------
__global__ void fill_kernel(const int* __restrict__ src, const int* __restrict__ dst,
                            const int* __restrict__ off, const int* __restrict__ rank,
                            int* __restrict__ adj) {
  int e4 = blockIdx.x * 256 + threadIdx.x;
  if (e4 >= NE / 4) return;
  int4 d = reinterpret_cast<const int4*>(dst)[e4];
  int4 s = reinterpret_cast<const int4*>(src)[e4];
  int4 r = reinterpret_cast<const int4*>(rank)[e4];
  adj[off[d.x] + r.x] = s.x;
  adj[off[d.y] + r.y] = s.y;
  adj[off[d.z] + r.z] = s.z;
  adj[off[d.w] + r.w] = s.w;
}

// ---------------- gather-mean, 4 nodes/wave, float4 rows --------------------
__launch_bounds__(256)
__global__ void gather_kernel(const float* __restrict__ x,
                              const int* __restrict__ off,
                              const int* __restrict__ deg,
                              const int* __restrict__ adj,
                              float* __restrict__ prop) {
  const float4* X = reinterpret_cast<const float4*>(x);
  int wid = (blockIdx.x * 256 + threadIdx.x) >> 6;
  int nwaves = (gridDim.x * 256) >> 6;
  int lane = threadIdx.x & 63;
  int g = lane >> 4;                 // node within quad
  int s = lane & 15;                 // float4 slot within row
  const int NQUAD = NN / 4;          // 25000
  for (int q = wid; q < NQUAD; q += nwaves) {
    int n = q * 4 + g;
    int start = off[n];
    int d = deg[n];
    float4 a0 = {0,0,0,0}, a1 = {0,0,0,0}, a2 = {0,0,0,0}, a3 = {0,0,0,0};
    int t = 0;
    for (; t + 4 <= d; t += 4) {
      int i0 = adj[start + t + 0];
      int i1 = adj[start + t + 1];
      int i2 = adj[start + t + 2];
      int i3 = adj[start + t + 3];
      float4 v0 = X[i0 * 16 + s];
      float4 v1 = X[i1 * 16 + s];
      float4 v2 = X[i2 * 16 + s];
      float4 v3 = X[i3 * 16 + s];
      a0.x += v0.x; a0.y += v0.y; a0.z += v0.z; a0.w += v0.w;
      a1.x += v1.x; a1.y += v1.y; a1.z += v1.z; a1.w += v1.w;
      a2.x += v2.x; a2.y += v2.y; a2.z += v2.z; a2.w += v2.w;
      a3.x += v3.x; a3.y += v3.y; a3.z += v3.z; a3.w += v3.w;
    }
    if (t < d) {                     // tail <=3 rows, clamp + mask
      int dm = d - 1;
      int u1 = (t + 1 < d) ? t + 1 : dm;
      int u2 = (t + 2 < d) ? t + 2 : dm;
      int i0 = adj[start + t];
      int i1 = adj[start + u1];
      int i2 = adj[start + u2];
      float4 v0 = X[i0 * 16 + s];
      float4 v1 = X[i1 * 16 + s];
      float4 v2 = X[i2 * 16 + s];
      a0.x += v0.x; a0.y += v0.y; a0.z += v0.z; a0.w += v0.w;
      if (t + 1 < d) { a1.x += v1.x; a1.y += v1.y; a1.z += v1.z; a1.w += v1.w; }
      if (t + 2 < d) { a2.x += v2.x; a2.y += v2.y; a2.z += v2.z; a2.w += v2.w; }
    }
    float rc = 1.0f / fmaxf((float)d, 1.0f);
    float4 r;
    r.x = ((a0.x + a1.x) + (a2.x + a3.x)) * rc;
    r.y = ((a0.y + a1.y) + (a2.y + a3.y)) * rc;
    r.z = ((a0.z + a1.z) + (a2.z + a3.z)) * rc;
    r.w = ((a0.w + a1.w) + (a2.w + a3.w)) * rc;
    reinterpret_cast<float4*>(prop)[n * 16 + s] = r;   // 1KB/wave contiguous
  }
}

// ---------------- light SAGE GEMM: out = relu(norm(tmp + prop@wr.T)) --------
// tmp (self-term incl. bias) is already in output form -> no sp staging,
// half the FMAs, LDS 32KB. In-place on out: read/write same-thread cell.
__launch_bounds__(512, 4)
__global__ void gemm_light_kernel(float* __restrict__ out,
                                  const float* __restrict__ prop,
                                  const float* __restrict__ wr) {
  __shared__ float wrA[DD * DD] __attribute__((aligned(16)));  // [k][j]
  __shared__ float pp[8][8][DD] __attribute__((aligned(16)));
  int tid = threadIdx.x;
  int j = tid & 63;
  int w = tid >> 6;

  for (int i = tid; i < DD * DD; i += 512) {
    int jj = i >> 6, kk = i & 63;
    wrA[kk * DD + jj] = wr[i];
  }
  __syncthreads();

  const int ngrp = (NOCT + 7) / 8;   // 1563
  for (int grp = blockIdx.x; grp < ngrp; grp += gridDim.x) {
    int o = grp * 8 + w;
    if (o >= NOCT) continue;
    int n0 = o * 8;

    float acc[8];
    #pragma unroll
    for (int i = 0; i < 8; ++i) {
      pp[w][i][j] = prop[(size_t)(n0 + i) * DD + j];
      acc[i] = out[(size_t)(n0 + i) * DD + j];       // tmp1 = self + bias
    }

    #pragma unroll
    for (int q = 0; q < 16; ++q) {
      int kb = q * 4;
      float w0 = wrA[(kb + 0) * DD + j];
      float w1v = wrA[(kb + 1) * DD + j];
      float w2v = wrA[(kb + 2) * DD + j];
      float w3v = wrA[(kb + 3) * DD + j];
      #pragma unroll
      for (int i = 0; i < 8; ++i) {
        float4 pv = *(const float4*)&pp[w][i][kb];   // broadcast
        float a = acc[i];
        a = fmaf(pv.x, w0, a);
        a = fmaf(pv.y, w1v, a);
        a = fmaf(pv.z, w2v, a);
        a = fmaf(pv.w, w3v, a);
        acc[i] = a;
      }
    }

    #pragma unroll
    for (int i = 0; i < 8; ++i) {
      float a = acc[i];
      float ss = a * a;
      #pragma unroll
      for (int o2 = 32; o2 > 0; o2 >>= 1) ss += __shfl_xor(ss, o2, 64);
      float ov = a / fmaxf(sqrtf(ss), 1e-12f);
      ov = fmaxf(ov, 0.0f);
      out[(size_t)(n0 + i) * DD + j] = ov;
    }
  }
}

// ---------------- full SAGE GEMM (layer 2): relu(norm(x@wl.T+prop@wr.T+b)) --
__launch_bounds__(512, 4)
__global__ void sage_gemm_kernel(const float* __restrict__ xin,
                                 const float* __restrict__ prop,
                                 const float* __restrict__ wl,
                                 const float* __restrict__ bl,
                                 const float* __restrict__ wr,
                                 const float* __restrict__ br,
                                 float* __restrict__ out) {
  __shared__ float wlA[DD * DD] __attribute__((aligned(16)));  // [k][j]
  __shared__ float wrA[DD * DD] __attribute__((aligned(16)));  // [k][j]
  __shared__ float sp[8][8][DD] __attribute__((aligned(16)));
  __shared__ float pp[8][8][DD] __attribute__((aligned(16)));
  int tid = threadIdx.x;
  int j = tid & 63;
  int w = tid >> 6;

  for (int i = tid; i < DD * DD; i += 512) {
    int jj = i >> 6, kk = i & 63;
    wlA[kk * DD + jj] = wl[i];
    wrA[kk * DD + jj] = wr[i];
  }
  float bias = bl[j] + br[j];
  __syncthreads();

  const int ngrp = (NOCT + 7) / 8;   // 1563
  for (int grp = blockIdx.x; grp < ngrp; grp += gridDim.x) {
    int o = grp * 8 + w;
    if (o >= NOCT) continue;
    int n0 = o * 8;

    #pragma unroll
    for (int i = 0; i < 8; ++i) {
      sp[w][i][j] = xin[(size_t)(n0 + i) * DD + j];
      pp[w][i][j] = prop[(size_t)(n0 + i) * DD + j];
    }

    float acc[8];
    #pragma unroll
    for (int i = 0; i < 8; ++i) acc[i] = bias;

    #pragma unroll
    for (int q = 0; q < 16; ++q) {
      int kb = q * 4;
      float wl0 = wlA[(kb + 0) * DD + j];
      float wl1 = wlA[(kb + 1) * DD + j];
      float wl2 = wlA[(kb + 2) * DD + j];
      float wl3 = wlA[(kb + 3) * DD + j];
      float wr0 = wrA[(kb + 0) * DD + j];
      float wr1 = wrA[(kb + 1) * DD + j];
      float wr2 = wrA[(kb + 2) * DD + j];
      float wr3 = wrA[(kb + 3) * DD + j];
      #pragma unroll
      for (int i = 0; i < 8; ++i) {
        float4 sv = *(const float4*)&sp[w][i][kb];   // broadcast
        float4 pv = *(const float4*)&pp[w][i][kb];   // broadcast
        float a = acc[i];
        a = fmaf(sv.x, wl0, a);
        a = fmaf(sv.y, wl1, a);
        a = fmaf(sv.z, wl2, a);
        a = fmaf(sv.w, wl3, a);
        a = fmaf(pv.x, wr0, a);
        a = fmaf(pv.y, wr1, a);
        a = fmaf(pv.z, wr2, a);
        a = fmaf(pv.w, wr3, a);
        acc[i] = a;
      }
    }

    #pragma unroll
    for (int i = 0; i < 8; ++i) {
      float a = acc[i];
      float ss = a * a;
      #pragma unroll
      for (int o2 = 32; o2 > 0; o2 >>= 1) ss += __shfl_xor(ss, o2, 64);
      float ov = a / fmaxf(sqrtf(ss), 1e-12f);
      ov = fmaxf(ov, 0.0f);
      out[(size_t)(n0 + i) * DD + j] = ov;
    }
  }
}

// ---------------- post-MLP as a single folded GEMM (in-place safe) ----------
__launch_bounds__(512, 4)
__global__ void post_kernel(const float* __restrict__ h,
                            const float* __restrict__ wc,
                            const float* __restrict__ bc,
                            float* __restrict__ out) {
  __shared__ float wA[DD * DD] __attribute__((aligned(16)));   // [k][j]
  __shared__ float hp[8][8][DD] __attribute__((aligned(16)));
  int tid = threadIdx.x;
  int j = tid & 63;
  int w = tid >> 6;

  for (int i = tid; i < DD * DD; i += 512) {
    int jj = i >> 6, kk = i & 63;
    wA[kk * DD + jj] = wc[i];
  }
  float bb = bc[j];
  __syncthreads();

  const int ngrp = (NOCT + 7) / 8;
  for (int grp = blockIdx.x; grp < ngrp; grp += gridDim.x) {
    int o = grp * 8 + w;
    if (o >= NOCT) continue;
    int n0 = o * 8;
    #pragma unroll
    for (int i = 0; i < 8; ++i) hp[w][i][j] = h[(size_t)(n0 + i) * DD + j];

    float acc[8];
    #pragma unroll
    for (int i = 0; i < 8; ++i) acc[i] = bb;
    #pragma unroll
    for (int q = 0; q < 16; ++q) {
      int kb = q * 4;
      float w0 = wA[(kb + 0) * DD + j];
      float w1v = wA[(kb + 1) * DD + j];
      float w2v = wA[(kb + 2) * DD + j];
      float w3v = wA[(kb + 3) * DD + j];
      #pragma unroll
      for (int i = 0; i < 8; ++i) {
        float4 hv = *(const float4*)&hp[w][i][kb];
        float a = acc[i];
        a = fmaf(hv.x, w0, a);
        a = fmaf(hv.y, w1v, a);
        a = fmaf(hv.z, w2v, a);
        a = fmaf(hv.w, w3v, a);
        acc[i] = a;
      }
    }
    #pragma unroll
    for (int i = 0; i < 8; ++i) out[(size_t)(n0 + i) * DD + j] = acc[i];
  }
}

extern "C" void kernel_launch(void* const* d_in, const int* in_sizes, int n_in,
                              void* d_out, int out_size, void* d_ws, size_t ws_size,
                              hipStream_t stream) {
  const float* x   = (const float*)d_in[0];
  const int*   ei  = (const int*)d_in[1];
  const float* w1l = (const float*)d_in[2];
  const float* b1l = (const float*)d_in[3];
  const float* w1r = (const float*)d_in[4];
  const float* b1r = (const float*)d_in[5];
  const float* w2l = (const float*)d_in[6];
  const float* b2l = (const float*)d_in[7];
  const float* w2r = (const float*)d_in[8];
  const float* b2r = (const float*)d_in[9];
  const float* wp1 = (const float*)d_in[10];
  const float* bp1 = (const float*)d_in[11];
  const float* wp2 = (const float*)d_in[12];
  const float* bp2 = (const float*)d_in[13];
  float* out = (float*)d_out;

  const int* src = ei;
  const int* dst = ei + NE;

  // ws (4B units): deg[102400] | off[102400] | bsum[1024] | wc[4096] | bc[1024]
  //               | adj[NE] | prop[NN*DD]
  // rank aliases prop (dead before gather writes prop).
  int* deg   = (int*)d_ws;
  int* off   = deg + 102400;
  int* bsum  = off + 102400;
  float* wc  = (float*)(bsum + 1024);
  float* bc  = wc + 4096;
  int* adj   = (int*)(bc + 1024);
  float* prop = (float*)(adj + NE);
  int* rank  = (int*)prop;                 // [NE]

  const int e4grid = (NE / 4 + 255) / 256;   // 1563

  // ---- CSR build (hist) || layer-1 self-GEMM (tmp1 -> out) || combine ----
  zero_kernel<<<256, 256, 0, stream>>>(deg, 102400);
  mega1_kernel<<<NH + NG1 + 1, 256, 0, stream>>>(dst, deg, rank,
                                                 x, w1l, b1l, b1r, out,
                                                 wp1, bp1, wp2, bp2, wc, bc);
  scan1_kernel<<<NBLK, SCAN_BS, 0, stream>>>(deg, off, bsum);
  scan2_kernel<<<1, 512, 0, stream>>>(bsum);
  scan3_kernel<<<NBLK, SCAN_BS, 0, stream>>>(off, bsum);
  fill_kernel<<<e4grid, 256, 0, stream>>>(src, dst, off, rank, adj);

  // ---- layer 1: gather(x)->prop; out = relu(norm(tmp1 + prop@w1r.T)) ----
  gather_kernel<<<2048, 256, 0, stream>>>(x, off, deg, adj, prop);
  gemm_light_kernel<<<1024, 512, 0, stream>>>(out, prop, w1r);

  // ---- layer 2: gather(out)->prop; full gemm (in-place safe) ----
  gather_kernel<<<2048, 256, 0, stream>>>(out, off, deg, adj, prop);
  sage_gemm_kernel<<<512, 512, 0, stream>>>(out, prop, w2l, b2l, w2r, b2r, out);

  // ---- post-MLP (single folded GEMM, in-place) ----
  post_kernel<<<512, 512, 0, stream>>>(out, wc, bc, out);
}

// Round 11
// 325.206 us; speedup vs baseline: 1.1673x; 1.1006x over previous
//
#include <hip/hip_runtime.h>

#define NN 100000
#define NE 1600000
#define DD 64
#define NB 196                             // coarse buckets (dst>>9)
#define BKT 512                            // nodes per bucket
#define NOCT 12500                         // NN / 8 nodes-per-wave (gemm)
#define NH 391                             // edge-pass blocks (4 int4/thread)
#define NG1 1024                           // self-GEMM blocks

// ---------------- zero ----------------
__global__ void zero_kernel(int* __restrict__ p, int n) {
  int i = blockIdx.x * blockDim.x + threadIdx.x;
  int stride = gridDim.x * blockDim.x;
  for (; i < n; i += stride) p[i] = 0;
}

// ---------------- pass 1: coarse histogram (LDS atomics) --------------------
__launch_bounds__(256)
__global__ void chist_kernel(const int* __restrict__ dst, int* __restrict__ gcount) {
  __shared__ int lh[NB];
  const int NQ = NE / 4;
  int t = blockIdx.x * 256 + threadIdx.x;
  const int nt = NH * 256;
  for (int i = threadIdx.x; i < NB; i += 256) lh[i] = 0;
  __syncthreads();
  #pragma unroll
  for (int k = 0; k < 4; ++k) {
    int idx = t + k * nt;
    if (idx < NQ) {
      int4 d = reinterpret_cast<const int4*>(dst)[idx];
      atomicAdd(&lh[d.x >> 9], 1);
      atomicAdd(&lh[d.y >> 9], 1);
      atomicAdd(&lh[d.z >> 9], 1);
      atomicAdd(&lh[d.w >> 9], 1);
    }
  }
  __syncthreads();
  for (int i = threadIdx.x; i < NB; i += 256)
    if (lh[i]) atomicAdd(&gcount[i], lh[i]);
}

// ---------------- coarse scan: gbase (exclusive, +sentinel), gcursor --------
__global__ void cscan_kernel(const int* __restrict__ gcount,
                             int* __restrict__ gbase, int* __restrict__ gcursor) {
  __shared__ int wsum[4];
  int t = threadIdx.x, lane = t & 63, w = t >> 6;
  int v = (t < NB) ? gcount[t] : 0;
  int incl = v;
  #pragma unroll
  for (int o = 1; o < 64; o <<= 1) {
    int u = __shfl_up(incl, o, 64);
    if (lane >= o) incl += u;
  }
  if (lane == 63) wsum[w] = incl;
  __syncthreads();
  int prefix = 0;
  for (int u = 0; u < w; ++u) prefix += wsum[u];
  int excl = prefix + incl - v;
  if (t < NB) { gbase[t] = excl; gcursor[t] = excl; }
  if (t == NB - 1) gbase[NB] = excl + v;       // = NE
}

// ---------------- pass 2: scatter (src,dst) into bucket segments ------------
// Per block: LDS hist -> one returning global atomic per touched bucket
// (reserve segment) -> LDS-cursor scatter. 76K global atomics vs 1.6M.
__launch_bounds__(256)
__global__ void scatter2_kernel(const int* __restrict__ src, const int* __restrict__ dst,
                                int* __restrict__ gcursor, int2* __restrict__ pairs) {
  __shared__ int lh[NB];
  __shared__ int lbase[NB];
  __shared__ int lcur[NB];
  const int NQ = NE / 4;
  int t = blockIdx.x * 256 + threadIdx.x;
  const int nt = NH * 256;
  for (int i = threadIdx.x; i < NB; i += 256) lh[i] = 0;
  __syncthreads();
  int4 dv[4], sv[4];
  bool pv[4];
  #pragma unroll
  for (int k = 0; k < 4; ++k) {
    int idx = t + k * nt;
    pv[k] = idx < NQ;
    if (pv[k]) {
      dv[k] = reinterpret_cast<const int4*>(dst)[idx];
      sv[k] = reinterpret_cast<const int4*>(src)[idx];
      atomicAdd(&lh[dv[k].x >> 9], 1);
      atomicAdd(&lh[dv[k].y >> 9], 1);
      atomicAdd(&lh[dv[k].z >> 9], 1);
      atomicAdd(&lh[dv[k].w >> 9], 1);
    }
  }
  __syncthreads();
  for (int i = threadIdx.x; i < NB; i += 256) {
    lcur[i] = 0;
    lbase[i] = lh[i] ? atomicAdd(&gcursor[i], lh[i]) : 0;
  }
  __syncthreads();
  #pragma unroll
  for (int k = 0; k < 4; ++k) {
    if (pv[k]) {
      int b;
      b = dv[k].x >> 9; pairs[lbase[b] + atomicAdd(&lcur[b], 1)] = make_int2(sv[k].x, dv[k].x);
      b = dv[k].y >> 9; pairs[lbase[b] + atomicAdd(&lcur[b], 1)] = make_int2(sv[k].y, dv[k].y);
      b = dv[k].z >> 9; pairs[lbase[b] + atomicAdd(&lcur[b], 1)] = make_int2(sv[k].z, dv[k].z);
      b = dv[k].w >> 9; pairs[lbase[b] + atomicAdd(&lcur[b], 1)] = make_int2(sv[k].w, dv[k].w);
    }
  }
}

// ---------------- pass 3: per-bucket exact CSR (all LDS) --------------------
// Block b handles pairs[gbase[b], gbase[b+1]): 512-bin LDS hist -> wave scan
// -> deg/off out -> LDS-cursor placement of src into adj (bucket segment).
__launch_bounds__(256)
__global__ void csr_kernel(const int2* __restrict__ pairs, const int* __restrict__ gbase,
                           int* __restrict__ deg, int* __restrict__ off,
                           int* __restrict__ adj) {
  __shared__ int lh[BKT];
  __shared__ int wsum[4];
  int b = blockIdx.x;
  int t = threadIdx.x;
  int rs = gbase[b], re = gbase[b + 1];
  lh[2 * t] = 0;
  lh[2 * t + 1] = 0;
  __syncthreads();
  for (int i = rs + t; i < re; i += 256)
    atomicAdd(&lh[pairs[i].y - b * BKT], 1);
  __syncthreads();
  // exclusive scan over 512 bins (2 bins/thread, 4-wave scan)
  int lane = t & 63, w = t >> 6;
  int h0 = lh[2 * t], h1 = lh[2 * t + 1];
  int s = h0 + h1, incl = s;
  #pragma unroll
  for (int o = 1; o < 64; o <<= 1) {
    int u = __shfl_up(incl, o, 64);
    if (lane >= o) incl += u;
  }
  if (lane == 63) wsum[w] = incl;
  __syncthreads();                          // after this, lh reads are done
  int prefix = 0;
  for (int u = 0; u < w; ++u) prefix += wsum[u];
  int excl = prefix + incl - s;
  // deg/off out + cursors (reuse lh, init at exclusive offsets)
  int n0 = b * BKT + 2 * t, n1 = n0 + 1;
  if (n0 < NN) { deg[n0] = h0; off[n0] = rs + excl; }
  if (n1 < NN) { deg[n1] = h1; off[n1] = rs + excl + h0; }
  lh[2 * t] = excl;
  lh[2 * t + 1] = excl + h0;
  __syncthreads();
  for (int i = rs + t; i < re; i += 256) {
    int2 e = pairs[i];
    int pos = atomicAdd(&lh[e.y - b * BKT], 1);
    adj[rs + pos] = e.x;
  }
}

// ---------------- layer1 self-GEMM (tmp1 = x@w1l.T + b1l+b1r) || combine ----
__launch_bounds__(256)
__global__ void selfgemm_kernel(const float* __restrict__ x,
                                const float* __restrict__ wl,
                                const float* __restrict__ bl,
                                const float* __restrict__ br,
                                float* __restrict__ tmp,
                                const float* __restrict__ wp1, const float* __restrict__ bp1,
                                const float* __restrict__ wp2, const float* __restrict__ bp2,
                                float* __restrict__ wc, float* __restrict__ bc) {
  __shared__ float wA[DD * DD] __attribute__((aligned(16)));
  __shared__ float sp[4][8][DD] __attribute__((aligned(16)));
  int bid = blockIdx.x;
  if (bid < NG1) {
    int tid = threadIdx.x;
    int j = tid & 63;
    int w = tid >> 6;                      // 0..3
    for (int i = tid; i < DD * DD; i += 256) {
      int jj = i >> 6, kk = i & 63;
      wA[kk * DD + jj] = wl[i];
    }
    float bias = bl[j] + br[j];
    __syncthreads();
    const int ngrp = 3125;                 // 100000 / (4 waves * 8 nodes)
    for (int grp = bid; grp < ngrp; grp += NG1) {
      int n0 = (grp * 4 + w) * 8;
      #pragma unroll
      for (int i = 0; i < 8; ++i) sp[w][i][j] = x[(size_t)(n0 + i) * DD + j];
      float acc[8];
      #pragma unroll
      for (int i = 0; i < 8; ++i) acc[i] = bias;
      #pragma unroll
      for (int q = 0; q < 16; ++q) {
        int kb = q * 4;
        float w0 = wA[(kb + 0) * DD + j];
        float w1v = wA[(kb + 1) * DD + j];
        float w2v = wA[(kb + 2) * DD + j];
        float w3v = wA[(kb + 3) * DD + j];
        #pragma unroll
        for (int i = 0; i < 8; ++i) {
          float4 sv = *(const float4*)&sp[w][i][kb];
          float a = acc[i];
          a = fmaf(sv.x, w0, a);
          a = fmaf(sv.y, w1v, a);
          a = fmaf(sv.z, w2v, a);
          a = fmaf(sv.w, w3v, a);
          acc[i] = a;
        }
      }
      #pragma unroll
      for (int i = 0; i < 8; ++i) tmp[(size_t)(n0 + i) * DD + j] = acc[i];
    }
  } else {
    int t = threadIdx.x;
    for (int idx = t; idx < DD * DD; idx += 256) {
      int jp = idx >> 6, k = idx & 63;
      float s = 0.f;
      #pragma unroll
      for (int m = 0; m < DD; ++m) s = fmaf(wp2[jp * DD + m], wp1[m * DD + k], s);
      wc[idx] = s;
    }
    if (t < DD) {
      float s = bp2[t];
      #pragma unroll
      for (int m = 0; m < DD; ++m) s = fmaf(wp2[t * DD + m], bp1[m], s);
      bc[t] = s;
    }
  }
}

// ---------------- gather-mean, 4 nodes/wave, float4 rows --------------------
__launch_bounds__(256)
__global__ void gather_kernel(const float* __restrict__ x,
                              const int* __restrict__ off,
                              const int* __restrict__ deg,
                              const int* __restrict__ adj,
                              float* __restrict__ prop) {
  const float4* X = reinterpret_cast<const float4*>(x);
  int wid = (blockIdx.x * 256 + threadIdx.x) >> 6;
  int nwaves = (gridDim.x * 256) >> 6;
  int lane = threadIdx.x & 63;
  int g = lane >> 4;
  int s = lane & 15;
  const int NQUAD = NN / 4;
  for (int q = wid; q < NQUAD; q += nwaves) {
    int n = q * 4 + g;
    int start = off[n];
    int d = deg[n];
    float4 a0 = {0,0,0,0}, a1 = {0,0,0,0}, a2 = {0,0,0,0}, a3 = {0,0,0,0};
    int t = 0;
    for (; t + 4 <= d; t += 4) {
      int i0 = adj[start + t + 0];
      int i1 = adj[start + t + 1];
      int i2 = adj[start + t + 2];
      int i3 = adj[start + t + 3];
      float4 v0 = X[i0 * 16 + s];
      float4 v1 = X[i1 * 16 + s];
      float4 v2 = X[i2 * 16 + s];
      float4 v3 = X[i3 * 16 + s];
      a0.x += v0.x; a0.y += v0.y; a0.z += v0.z; a0.w += v0.w;
      a1.x += v1.x; a1.y += v1.y; a1.z += v1.z; a1.w += v1.w;
      a2.x += v2.x; a2.y += v2.y; a2.z += v2.z; a2.w += v2.w;
      a3.x += v3.x; a3.y += v3.y; a3.z += v3.z; a3.w += v3.w;
    }
    if (t < d) {
      int dm = d - 1;
      int u1 = (t + 1 < d) ? t + 1 : dm;
      int u2 = (t + 2 < d) ? t + 2 : dm;
      int i0 = adj[start + t];
      int i1 = adj[start + u1];
      int i2 = adj[start + u2];
      float4 v0 = X[i0 * 16 + s];
      float4 v1 = X[i1 * 16 + s];
      float4 v2 = X[i2 * 16 + s];
      a0.x += v0.x; a0.y += v0.y; a0.z += v0.z; a0.w += v0.w;
      if (t + 1 < d) { a1.x += v1.x; a1.y += v1.y; a1.z += v1.z; a1.w += v1.w; }
      if (t + 2 < d) { a2.x += v2.x; a2.y += v2.y; a2.z += v2.z; a2.w += v2.w; }
    }
    float rc = 1.0f / fmaxf((float)d, 1.0f);
    float4 r;
    r.x = ((a0.x + a1.x) + (a2.x + a3.x)) * rc;
    r.y = ((a0.y + a1.y) + (a2.y + a3.y)) * rc;
    r.z = ((a0.z + a1.z) + (a2.z + a3.z)) * rc;
    r.w = ((a0.w + a1.w) + (a2.w + a3.w)) * rc;
    reinterpret_cast<float4*>(prop)[n * 16 + s] = r;
  }
}

// ---------------- light SAGE GEMM: out = relu(norm(tmp + prop@wr.T)) --------
__launch_bounds__(512, 4)
__global__ void gemm_light_kernel(float* __restrict__ out,
                                  const float* __restrict__ prop,
                                  const float* __restrict__ wr) {
  __shared__ float wrA[DD * DD] __attribute__((aligned(16)));
  __shared__ float pp[8][8][DD] __attribute__((aligned(16)));
  int tid = threadIdx.x;
  int j = tid & 63;
  int w = tid >> 6;

  for (int i = tid; i < DD * DD; i += 512) {
    int jj = i >> 6, kk = i & 63;
    wrA[kk * DD + jj] = wr[i];
  }
  __syncthreads();

  const int ngrp = (NOCT + 7) / 8;
  for (int grp = blockIdx.x; grp < ngrp; grp += gridDim.x) {
    int o = grp * 8 + w;
    if (o >= NOCT) continue;
    int n0 = o * 8;

    float acc[8];
    #pragma unroll
    for (int i = 0; i < 8; ++i) {
      pp[w][i][j] = prop[(size_t)(n0 + i) * DD + j];
      acc[i] = out[(size_t)(n0 + i) * DD + j];
    }

    #pragma unroll
    for (int q = 0; q < 16; ++q) {
      int kb = q * 4;
      float w0 = wrA[(kb + 0) * DD + j];
      float w1v = wrA[(kb + 1) * DD + j];
      float w2v = wrA[(kb + 2) * DD + j];
      float w3v = wrA[(kb + 3) * DD + j];
      #pragma unroll
      for (int i = 0; i < 8; ++i) {
        float4 pv = *(const float4*)&pp[w][i][kb];
        float a = acc[i];
        a = fmaf(pv.x, w0, a);
        a = fmaf(pv.y, w1v, a);
        a = fmaf(pv.z, w2v, a);
        a = fmaf(pv.w, w3v, a);
        acc[i] = a;
      }
    }

    #pragma unroll
    for (int i = 0; i < 8; ++i) {
      float a = acc[i];
      float ss = a * a;
      #pragma unroll
      for (int o2 = 32; o2 > 0; o2 >>= 1) ss += __shfl_xor(ss, o2, 64);
      float ov = a / fmaxf(sqrtf(ss), 1e-12f);
      ov = fmaxf(ov, 0.0f);
      out[(size_t)(n0 + i) * DD + j] = ov;
    }
  }
}

// ---------------- full SAGE GEMM (layer 2) ----------------------------------
__launch_bounds__(512, 4)
__global__ void sage_gemm_kernel(const float* __restrict__ xin,
                                 const float* __restrict__ prop,
                                 const float* __restrict__ wl,
                                 const float* __restrict__ bl,
                                 const float* __restrict__ wr,
                                 const float* __restrict__ br,
                                 float* __restrict__ out) {
  __shared__ float wlA[DD * DD] __attribute__((aligned(16)));
  __shared__ float wrA[DD * DD] __attribute__((aligned(16)));
  __shared__ float sp[8][8][DD] __attribute__((aligned(16)));
  __shared__ float pp[8][8][DD] __attribute__((aligned(16)));
  int tid = threadIdx.x;
  int j = tid & 63;
  int w = tid >> 6;

  for (int i = tid; i < DD * DD; i += 512) {
    int jj = i >> 6, kk = i & 63;
    wlA[kk * DD + jj] = wl[i];
    wrA[kk * DD + jj] = wr[i];
  }
  float bias = bl[j] + br[j];
  __syncthreads();

  const int ngrp = (NOCT + 7) / 8;
  for (int grp = blockIdx.x; grp < ngrp; grp += gridDim.x) {
    int o = grp * 8 + w;
    if (o >= NOCT) continue;
    int n0 = o * 8;

    #pragma unroll
    for (int i = 0; i < 8; ++i) {
      sp[w][i][j] = xin[(size_t)(n0 + i) * DD + j];
      pp[w][i][j] = prop[(size_t)(n0 + i) * DD + j];
    }

    float acc[8];
    #pragma unroll
    for (int i = 0; i < 8; ++i) acc[i] = bias;

    #pragma unroll
    for (int q = 0; q < 16; ++q) {
      int kb = q * 4;
      float wl0 = wlA[(kb + 0) * DD + j];
      float wl1 = wlA[(kb + 1) * DD + j];
      float wl2 = wlA[(kb + 2) * DD + j];
      float wl3 = wlA[(kb + 3) * DD + j];
      float wr0 = wrA[(kb + 0) * DD + j];
      float wr1 = wrA[(kb + 1) * DD + j];
      float wr2 = wrA[(kb + 2) * DD + j];
      float wr3 = wrA[(kb + 3) * DD + j];
      #pragma unroll
      for (int i = 0; i < 8; ++i) {
        float4 sv = *(const float4*)&sp[w][i][kb];
        float4 pv = *(const float4*)&pp[w][i][kb];
        float a = acc[i];
        a = fmaf(sv.x, wl0, a);
        a = fmaf(sv.y, wl1, a);
        a = fmaf(sv.z, wl2, a);
        a = fmaf(sv.w, wl3, a);
        a = fmaf(pv.x, wr0, a);
        a = fmaf(pv.y, wr1, a);
        a = fmaf(pv.z, wr2, a);
        a = fmaf(pv.w, wr3, a);
        acc[i] = a;
      }
    }

    #pragma unroll
    for (int i = 0; i < 8; ++i) {
      float a = acc[i];
      float ss = a * a;
      #pragma unroll
      for (int o2 = 32; o2 > 0; o2 >>= 1) ss += __shfl_xor(ss, o2, 64);
      float ov = a / fmaxf(sqrtf(ss), 1e-12f);
      ov = fmaxf(ov, 0.0f);
      out[(size_t)(n0 + i) * DD + j] = ov;
    }
  }
}

// ---------------- post-MLP as a single folded GEMM --------------------------
__launch_bounds__(512, 4)
__global__ void post_kernel(const float* __restrict__ h,
                            const float* __restrict__ wc,
                            const float* __restrict__ bc,
                            float* __restrict__ out) {
  __shared__ float wA[DD * DD] __attribute__((aligned(16)));
  __shared__ float hp[8][8][DD] __attribute__((aligned(16)));
  int tid = threadIdx.x;
  int j = tid & 63;
  int w = tid >> 6;

  for (int i = tid; i < DD * DD; i += 512) {
    int jj = i >> 6, kk = i & 63;
    wA[kk * DD + jj] = wc[i];
  }
  float bb = bc[j];
  __syncthreads();

  const int ngrp = (NOCT + 7) / 8;
  for (int grp = blockIdx.x; grp < ngrp; grp += gridDim.x) {
    int o = grp * 8 + w;
    if (o >= NOCT) continue;
    int n0 = o * 8;
    #pragma unroll
    for (int i = 0; i < 8; ++i) hp[w][i][j] = h[(size_t)(n0 + i) * DD + j];

    float acc[8];
    #pragma unroll
    for (int i = 0; i < 8; ++i) acc[i] = bb;
    #pragma unroll
    for (int q = 0; q < 16; ++q) {
      int kb = q * 4;
      float w0 = wA[(kb + 0) * DD + j];
      float w1v = wA[(kb + 1) * DD + j];
      float w2v = wA[(kb + 2) * DD + j];
      float w3v = wA[(kb + 3) * DD + j];
      #pragma unroll
      for (int i = 0; i < 8; ++i) {
        float4 hv = *(const float4*)&hp[w][i][kb];
        float a = acc[i];
        a = fmaf(hv.x, w0, a);
        a = fmaf(hv.y, w1v, a);
        a = fmaf(hv.z, w2v, a);
        a = fmaf(hv.w, w3v, a);
        acc[i] = a;
      }
    }
    #pragma unroll
    for (int i = 0; i < 8; ++i) out[(size_t)(n0 + i) * DD + j] = acc[i];
  }
}

extern "C" void kernel_launch(void* const* d_in, const int* in_sizes, int n_in,
                              void* d_out, int out_size, void* d_ws, size_t ws_size,
                              hipStream_t stream) {
  const float* x   = (const float*)d_in[0];
  const int*   ei  = (const int*)d_in[1];
  const float* w1l = (const float*)d_in[2];
  const float* b1l = (const float*)d_in[3];
  const float* w1r = (const float*)d_in[4];
  const float* b1r = (const float*)d_in[5];
  const float* w2l = (const float*)d_in[6];
  const float* b2l = (const float*)d_in[7];
  const float* w2r = (const float*)d_in[8];
  const float* b2r = (const float*)d_in[9];
  const float* wp1 = (const float*)d_in[10];
  const float* bp1 = (const float*)d_in[11];
  const float* wp2 = (const float*)d_in[12];
  const float* bp2 = (const float*)d_in[13];
  float* out = (float*)d_out;

  const int* src = ei;
  const int* dst = ei + NE;

  // ws (4B units): deg[102400] | off[102400] | aux[1024] | wc[4096] | bc[1024]
  //               | adj[NE] | prop[NN*DD]
  // aux: gcount[0..196) @0, gbase[197] @256, gcursor[196] @512
  // pairs (int2[NE] = 12.8MB) aliases prop (dead before gather writes prop).
  int* deg     = (int*)d_ws;
  int* off     = deg + 102400;
  int* aux     = off + 102400;
  int* gcount  = aux;
  int* gbase   = aux + 256;
  int* gcursor = aux + 512;
  float* wc    = (float*)(aux + 1024);
  float* bc    = wc + 4096;
  int* adj     = (int*)(bc + 1024);
  float* prop  = (float*)(adj + NE);
  int2* pairs  = (int2*)prop;

  // ---- CSR build via bucket sort (LDS atomics; no per-edge global atomics) --
  zero_kernel<<<1, 256, 0, stream>>>(aux, 1024);
  chist_kernel<<<NH, 256, 0, stream>>>(dst, gcount);
  cscan_kernel<<<1, 256, 0, stream>>>(gcount, gbase, gcursor);
  scatter2_kernel<<<NH, 256, 0, stream>>>(src, dst, gcursor, pairs);
  csr_kernel<<<NB, 256, 0, stream>>>(pairs, gbase, deg, off, adj);

  // ---- layer-1 self-GEMM (tmp1 -> out) + post-weight folding ----
  selfgemm_kernel<<<NG1 + 1, 256, 0, stream>>>(x, w1l, b1l, b1r, out,
                                               wp1, bp1, wp2, bp2, wc, bc);

  // ---- layer 1: gather(x)->prop; out = relu(norm(tmp1 + prop@w1r.T)) ----
  gather_kernel<<<2048, 256, 0, stream>>>(x, off, deg, adj, prop);
  gemm_light_kernel<<<1024, 512, 0, stream>>>(out, prop, w1r);

  // ---- layer 2: gather(out)->prop; full gemm (in-place safe) ----
  gather_kernel<<<2048, 256, 0, stream>>>(out, off, deg, adj, prop);
  sage_gemm_kernel<<<512, 512, 0, stream>>>(out, prop, w2l, b2l, w2r, b2r, out);

  // ---- post-MLP (single folded GEMM, in-place) ----
  post_kernel<<<512, 512, 0, stream>>>(out, wc, bc, out);
}